// Round 2
// baseline (19454.459 us; speedup 1.0000x reference)
//
#include <hip/hip_runtime.h>
#include <hip/hip_bf16.h>
#include <math.h>

constexpr int DIM = 128;
constexpr int NC = 1024;
constexpr int NS = 4;
constexpr int NVEC = 16 * 8192;
constexpr size_t QSIZE = (size_t)NVEC * DIM;
constexpr int BM = 128;            // vectors per block
constexpr int CHUNK = 64;          // codes per staged chunk
constexpr int NCHUNK = NC / CHUNK; // 16
constexpr int CAP = 24;            // candidate capacity per vector
constexpr float MARGIN = 0.125f;   // >= 2 * worst-case bf16 score error (~0.036)

typedef short bf16x8 __attribute__((ext_vector_type(8)));
typedef float f32x16 __attribute__((ext_vector_type(16)));

__device__ __forceinline__ short f2bf(float f) {
    __hip_bfloat16 h = __float2bfloat16(f);
    union { __hip_bfloat16 h; short s; } u;
    u.h = h;
    return u.s;
}

// numpy pairwise sum of squares for exactly 128 elements (8 stride-8 accums,
// tree combine, squares rounded separately).
template <typename PTR>
__device__ __forceinline__ float np_pairwise_sq128(PTR v) {
#pragma clang fp contract(off)
    float r[8];
#pragma unroll
    for (int j = 0; j < 8; ++j) { float sq = v[j] * v[j]; r[j] = sq; }
#pragma unroll
    for (int i = 8; i < DIM; i += 8) {
#pragma unroll
        for (int j = 0; j < 8; ++j) { float sq = v[i + j] * v[i + j]; r[j] = r[j] + sq; }
    }
    return ((r[0] + r[1]) + (r[2] + r[3])) + ((r[4] + r[5]) + (r[6] + r[7]));
}

// Prologue: exact fp32 code norms + bf16 copies of the codebooks.
__global__ __launch_bounds__(256) void rvq_prologue(
        const float* __restrict__ cb, short* __restrict__ cb_bf,
        float* __restrict__ cnorm) {
    int row = blockIdx.x * 256 + threadIdx.x;
    if (row >= NS * NC) return;
    const float* src = cb + (size_t)row * DIM;
    cnorm[row] = np_pairwise_sq128(src);
    short* dst = cb_bf + (size_t)row * DIM;
    for (int i = 0; i < DIM; ++i) dst[i] = f2bf(src[i]);
}

__global__ __launch_bounds__(256, 2) void rvq_main(
        const float* __restrict__ x,
        const float* __restrict__ cb,       // fp32 codebooks (exact path)
        const short* __restrict__ cb_bf,    // bf16 codebooks (MFMA path)
        const float* __restrict__ cnorm_ws, // exact code norms
        float* __restrict__ out) {          // q region doubles as residual buffer
    __shared__ short sA[2][CHUNK * DIM];        // 32KB: code chunk, frag-linear, dbuf
    __shared__ float s_cnorm[NC];               // 4KB
    __shared__ unsigned short s_cand[BM * CAP]; // 6KB
    __shared__ int s_cnt[BM];
    __shared__ int s_ovf[BM];
    __shared__ int s_idx[BM];
    __shared__ int s_ovlist[BM];
    __shared__ int s_ovn;

    const int tid = threadIdx.x;
    const int w = tid >> 6;      // wave 0..3
    const int l = tid & 63;      // lane
    const int l31 = l & 31;
    const int h = l >> 5;        // lane half
    const int cg = w & 1;        // code-group (32 codes of each 64-chunk)
    const int vg = w >> 1;       // vec-group (64 of 128 vectors)
    const int blockbase = blockIdx.x * BM;

    float* rbuf = out;  // fp32 residual lives in the q output region

#define FETCH(CH) do { \
    _Pragma("unroll") \
    for (int i = 0; i < 4; ++i) { \
        int slot = tid + i * 256; \
        int rt = slot >> 9, ks = (slot >> 6) & 7, ll = slot & 63; \
        int code = (CH) * CHUNK + rt * 32 + (ll & 31); \
        tmp[i] = *(const bf16x8*)(cbbf_s + (size_t)code * DIM + ks * 16 + (ll >> 5) * 8); \
    } } while (0)
#define WRITE(BUF) do { \
    _Pragma("unroll") \
    for (int i = 0; i < 4; ++i) { \
        int slot = tid + i * 256; \
        *(bf16x8*)&sA[(BUF)][slot * 8] = tmp[i]; \
    } } while (0)

    for (int s = 0; s < NS; ++s) {
        // ---- stage setup ----
        for (int i = tid; i < NC; i += 256) s_cnorm[i] = cnorm_ws[s * NC + i];
        for (int i = tid; i < BM; i += 256) { s_cnt[i] = 0; s_ovf[i] = 0; }
        if (tid == 0) s_ovn = 0;

        const float* rsrc = (s == 0) ? (x + (size_t)blockbase * DIM)
                                     : (rbuf + (size_t)blockbase * DIM);

        // B fragments (residuals) packed in regs with the SAME assumed k-map
        // as the A staging below -> k-layout errors cancel in the dot.
        bf16x8 breg[2][8];
#pragma unroll
        for (int tc = 0; tc < 2; ++tc) {
            int vec = vg * 64 + tc * 32 + l31;
            const float* p = rsrc + (size_t)vec * DIM + h * 8;
#pragma unroll
            for (int ks = 0; ks < 8; ++ks) {
                float4 f0 = *(const float4*)(p + ks * 16);
                float4 f1 = *(const float4*)(p + ks * 16 + 4);
                bf16x8 b;
                b[0] = f2bf(f0.x); b[1] = f2bf(f0.y); b[2] = f2bf(f0.z); b[3] = f2bf(f0.w);
                b[4] = f2bf(f1.x); b[5] = f2bf(f1.y); b[6] = f2bf(f1.z); b[7] = f2bf(f1.w);
                breg[tc][ks] = b;
            }
        }

        const short* cbbf_s = cb_bf + (size_t)s * NC * DIM;
        bf16x8 tmp[4];
        FETCH(0);
        WRITE(0);
        float runmin[2] = { INFINITY, INFINITY };
        f32x16 acc[2];
#pragma unroll
        for (int tc = 0; tc < 2; ++tc) {
#pragma unroll
            for (int j = 0; j < 16; ++j) acc[tc][j] = 0.f;
        }
        __syncthreads();

        int cur = 0;
        for (int ch = 0; ch < NCHUNK; ++ch) {
            bool pf = (ch + 1 < NCHUNK);
            if (pf) FETCH(ch + 1);  // loads in flight under compute (T14)
            const int cbase = ch * CHUNK + cg * 32;
            float4 cnq[4];
#pragma unroll
            for (int q = 0; q < 4; ++q)
                cnq[q] = *(const float4*)&s_cnorm[cbase + 4 * h + 8 * q];
            // GEMM: C[code][vec] += A(codes) x B(residuals)
#pragma unroll
            for (int ks = 0; ks < 8; ++ks) {
                bf16x8 a = *(const bf16x8*)&sA[cur][((cg * 8 + ks) * 64 + l) * 8];
                acc[0] = __builtin_amdgcn_mfma_f32_32x32x16_bf16(a, breg[0][ks], acc[0], 0, 0, 0);
                acc[1] = __builtin_amdgcn_mfma_f32_32x32x16_bf16(a, breg[1][ks], acc[1], 0, 0, 0);
            }
            // epilogue pass 1: scores + running min (per lane, per vec-slot)
#pragma unroll
            for (int tc = 0; tc < 2; ++tc) {
#pragma unroll
                for (int r = 0; r < 16; ++r) {
                    float sc = fmaf(acc[tc][r], -2.f, cnq[r >> 2][r & 3]);
                    acc[tc][r] = sc;
                    runmin[tc] = fminf(runmin[tc], sc);
                }
            }
            // pass 2: margin-append candidates
#pragma unroll
            for (int tc = 0; tc < 2; ++tc) {
                int vl = vg * 64 + tc * 32 + l31;
#pragma unroll
                for (int r = 0; r < 16; ++r) {
                    if (acc[tc][r] <= runmin[tc] + MARGIN) {
                        int code = cbase + (r & 3) + 8 * (r >> 2) + 4 * h;
                        int o = atomicAdd(&s_cnt[vl], 1);
                        if (o < CAP) s_cand[vl * CAP + o] = (unsigned short)code;
                        else s_ovf[vl] = 1;
                    }
                    acc[tc][r] = 0.f;
                }
            }
            if (pf) WRITE(cur ^ 1);
            __syncthreads();
            cur ^= 1;
        }

        // ---- exact fp32 re-rank (bit-matches numpy; round-1-verified recipe) ----
        if (tid < BM && !s_ovf[tid]) {
            int n = s_cnt[tid];
            int bidx = 0;
            if (n == 1) {
                bidx = s_cand[tid * CAP];
            } else if (n > 1) {
                unsigned short* cl = &s_cand[tid * CAP];
                for (int a = 1; a < n; ++a) {          // sort ascending (determinism)
                    unsigned short key = cl[a];
                    int b = a - 1;
                    while (b >= 0 && cl[b] > key) { cl[b + 1] = cl[b]; --b; }
                    cl[b + 1] = key;
                }
                const float* rv = rsrc + (size_t)tid * DIM;
                float rn = np_pairwise_sq128(rv);
                float best = INFINITY;
                for (int k = 0; k < n; ++k) {
                    int c = cl[k];
                    const float* cp = cb + ((size_t)s * NC + c) * DIM;
                    float a0 = 0.f;
                    for (int d = 0; d < DIM; ++d)
                        a0 = __builtin_fmaf(rv[d], cp[d], a0);
                    float dist = (rn + s_cnorm[c]) - 2.0f * a0;
                    if (dist < best) { best = dist; bidx = c; }  // strict <, ascending c
                }
            }
            s_idx[tid] = bidx;
        }
        __syncthreads();
        if (tid < BM && s_ovf[tid]) {
            int p = atomicAdd(&s_ovn, 1);
            s_ovlist[p] = tid;
        }
        __syncthreads();
        // rare overflow: wave-parallel exact scan over all 1024 codes
        for (int o = w; o < s_ovn; o += 4) {
            int vec = s_ovlist[o];
            const float* rv = rsrc + (size_t)vec * DIM;
            float rn = np_pairwise_sq128(rv);
            float best = INFINITY; int bidx = 0;
            for (int k = 0; k < 16; ++k) {
                int c = k * 64 + l;  // ascending within lane
                const float* cp = cb + ((size_t)s * NC + c) * DIM;
                float a0 = 0.f;
                for (int d = 0; d < DIM; ++d)
                    a0 = __builtin_fmaf(rv[d], cp[d], a0);
                float dist = (rn + s_cnorm[c]) - 2.0f * a0;
                if (dist < best) { best = dist; bidx = c; }
            }
#pragma unroll
            for (int off = 32; off >= 1; off >>= 1) {  // lexicographic (dist, idx) min
                float ob = __shfl_xor(best, off, 64);
                int oi = __shfl_xor(bidx, off, 64);
                if (ob < best || (ob == best && oi < bidx)) { best = ob; bidx = oi; }
            }
            if (l == 0) s_idx[vec] = bidx;
        }
        __syncthreads();

        // ---- residual update (exact fp32, elementwise) + index write ----
        {
            int vec = tid >> 1;
            int d0 = (tid & 1) * 64;
            int c = s_idx[vec];
            const float* rv = rsrc + (size_t)vec * DIM + d0;
            const float* cp = cb + ((size_t)s * NC + c) * DIM + d0;
            float* ro = rbuf + (size_t)(blockbase + vec) * DIM + d0;
            if (s < NS - 1) {
#pragma unroll
                for (int i = 0; i < 64; i += 4) {
                    float4 rr = *(const float4*)(rv + i);
                    float4 cc = *(const float4*)(cp + i);
                    float4 oo;
                    oo.x = rr.x - cc.x; oo.y = rr.y - cc.y;
                    oo.z = rr.z - cc.z; oo.w = rr.w - cc.w;
                    *(float4*)(ro + i) = oo;
                }
            } else {  // last stage: q = x - r_new
                const float* xv = x + (size_t)(blockbase + vec) * DIM + d0;
#pragma unroll
                for (int i = 0; i < 64; i += 4) {
                    float4 rr = *(const float4*)(rv + i);
                    float4 cc = *(const float4*)(cp + i);
                    float4 xx = *(const float4*)(xv + i);
                    float4 oo;
                    oo.x = xx.x - (rr.x - cc.x); oo.y = xx.y - (rr.y - cc.y);
                    oo.z = xx.z - (rr.z - cc.z); oo.w = xx.w - (rr.w - cc.w);
                    *(float4*)(ro + i) = oo;
                }
            }
            if (tid < BM)
                out[QSIZE + (size_t)s * NVEC + blockbase + tid] = (float)s_idx[tid];
        }
        __syncthreads();
    }
#undef FETCH
#undef WRITE
}

extern "C" void kernel_launch(void* const* d_in, const int* in_sizes, int n_in,
                              void* d_out, int out_size, void* d_ws, size_t ws_size,
                              hipStream_t stream) {
    const float* x  = (const float*)d_in[0];   // [16, 8192, 128] fp32
    const float* cb = (const float*)d_in[1];   // [4, 1024, 128] fp32
    short* cb_bf = (short*)d_ws;                                   // 1 MB
    float* cnorm = (float*)((char*)d_ws + (size_t)NS * NC * DIM * sizeof(short));
    float* out = (float*)d_out;

    rvq_prologue<<<(NS * NC + 255) / 256, 256, 0, stream>>>(cb, cb_bf, cnorm);
    rvq_main<<<NVEC / BM, 256, 0, stream>>>(x, cb, cb_bf, cnorm, out);
}

// Round 3
// 974.878 us; speedup vs baseline: 19.9558x; 19.9558x over previous
//
#include <hip/hip_runtime.h>
#include <hip/hip_bf16.h>
#include <math.h>

constexpr int DIM = 128;
constexpr int NC = 1024;
constexpr int NS = 4;
constexpr int NVEC = 16 * 8192;
constexpr size_t QSIZE = (size_t)NVEC * DIM;
constexpr int BM = 128;            // vectors per block
constexpr int CHUNK = 64;          // codes per staged chunk
constexpr int NCHUNK = NC / CHUNK; // 16
constexpr int CAP = 12;            // candidate capacity per vector
constexpr float MARGIN = 0.125f;   // >= 2 * worst-case bf16 score error (~0.044)

typedef short bf16x8 __attribute__((ext_vector_type(8)));
typedef float f32x16 __attribute__((ext_vector_type(16)));

__device__ __forceinline__ short f2bf(float f) {
    __hip_bfloat16 h = __float2bfloat16(f);
    union { __hip_bfloat16 h; short s; } u;
    u.h = h;
    return u.s;
}

// Order-preserving float->uint map (for LDS atomicMin on scores, which can be <0).
__device__ __forceinline__ unsigned fmap(float f) {
    unsigned u = __float_as_uint(f);
    return (u & 0x80000000u) ? ~u : (u | 0x80000000u);
}
__device__ __forceinline__ float funmap(unsigned k) {
    unsigned u = (k & 0x80000000u) ? (k & 0x7FFFFFFFu) : ~k;
    return __uint_as_float(u);
}

// numpy pairwise sum of squares for exactly 128 elements (8 stride-8 accums,
// tree combine, squares rounded separately).
template <typename PTR>
__device__ __forceinline__ float np_pairwise_sq128(PTR v) {
#pragma clang fp contract(off)
    float r[8];
#pragma unroll
    for (int j = 0; j < 8; ++j) { float sq = v[j] * v[j]; r[j] = sq; }
#pragma unroll
    for (int i = 8; i < DIM; i += 8) {
#pragma unroll
        for (int j = 0; j < 8; ++j) { float sq = v[i + j] * v[i + j]; r[j] = r[j] + sq; }
    }
    return ((r[0] + r[1]) + (r[2] + r[3])) + ((r[4] + r[5]) + (r[6] + r[7]));
}

// Prologue: exact fp32 code norms + bf16 copies of the codebooks.
__global__ __launch_bounds__(256) void rvq_prologue(
        const float* __restrict__ cb, short* __restrict__ cb_bf,
        float* __restrict__ cnorm) {
    int row = blockIdx.x * 256 + threadIdx.x;
    if (row >= NS * NC) return;
    const float* src = cb + (size_t)row * DIM;
    cnorm[row] = np_pairwise_sq128(src);
    short* dst = cb_bf + (size_t)row * DIM;
    for (int i = 0; i < DIM; ++i) dst[i] = f2bf(src[i]);
}

__global__ __launch_bounds__(256, 2) void rvq_main(
        const float* __restrict__ x,
        const float* __restrict__ cb,       // fp32 codebooks (exact path)
        const short* __restrict__ cb_bf,    // bf16 codebooks (MFMA path)
        const float* __restrict__ cnorm_ws, // exact code norms
        float* __restrict__ out) {          // q region doubles as residual buffer
    __shared__ short sA[2][CHUNK * DIM];        // 32KB: code chunk, frag-linear, dbuf
    __shared__ float s_cnorm[NC];               // 4KB
    __shared__ unsigned s_vmin[BM];             // mapped approx-min per vector
    __shared__ unsigned short s_cand[BM * CAP]; // 3KB
    __shared__ int s_cnt[BM];
    __shared__ int s_ovf[BM];
    __shared__ int s_idx[BM];
    __shared__ int s_ovlist[BM];
    __shared__ int s_ovn;

    const int tid = threadIdx.x;
    const int w = tid >> 6;      // wave 0..3
    const int l = tid & 63;      // lane
    const int l31 = l & 31;
    const int h = l >> 5;        // lane half
    const int cg = w & 1;        // code-group (32 codes of each 64-chunk)
    const int vg = w >> 1;       // vec-group (64 of 128 vectors)
    const int blockbase = blockIdx.x * BM;

    float* rbuf = out;  // fp32 residual lives in the q output region

#define FETCH(CH) do { \
    _Pragma("unroll") \
    for (int i = 0; i < 4; ++i) { \
        int slot = tid + i * 256; \
        int rt = slot >> 9, ks = (slot >> 6) & 7, ll = slot & 63; \
        int code = (CH) * CHUNK + rt * 32 + (ll & 31); \
        tmp[i] = *(const bf16x8*)(cbbf_s + (size_t)code * DIM + ks * 16 + (ll >> 5) * 8); \
    } } while (0)
#define WRITE(BUF) do { \
    _Pragma("unroll") \
    for (int i = 0; i < 4; ++i) { \
        int slot = tid + i * 256; \
        *(bf16x8*)&sA[(BUF)][slot * 8] = tmp[i]; \
    } } while (0)

#pragma unroll 1
    for (int s = 0; s < NS; ++s) {
        // ---- stage setup ----
        for (int i = tid; i < NC; i += 256) s_cnorm[i] = cnorm_ws[s * NC + i];
        for (int i = tid; i < BM; i += 256) {
            s_cnt[i] = 0; s_ovf[i] = 0; s_vmin[i] = 0xFFFFFFFFu;
        }
        if (tid == 0) s_ovn = 0;

        const float* rsrc = (s == 0) ? (x + (size_t)blockbase * DIM)
                                     : (rbuf + (size_t)blockbase * DIM);

        // B fragments (residuals), packed once per stage, reused by both sweeps.
        // Same assumed k-map as the A staging -> k-layout errors cancel.
        bf16x8 breg[2][8];
#pragma unroll
        for (int tc = 0; tc < 2; ++tc) {
            int vec = vg * 64 + tc * 32 + l31;
            const float* p = rsrc + (size_t)vec * DIM + h * 8;
#pragma unroll
            for (int ks = 0; ks < 8; ++ks) {
                float4 f0 = *(const float4*)(p + ks * 16);
                float4 f1 = *(const float4*)(p + ks * 16 + 4);
                bf16x8 b;
                b[0] = f2bf(f0.x); b[1] = f2bf(f0.y); b[2] = f2bf(f0.z); b[3] = f2bf(f0.w);
                b[4] = f2bf(f1.x); b[5] = f2bf(f1.y); b[6] = f2bf(f1.z); b[7] = f2bf(f1.w);
                breg[tc][ks] = b;
            }
        }

        const short* cbbf_s = cb_bf + (size_t)s * NC * DIM;
        bf16x8 tmp[4];
        float vthr[2];  // vmin + MARGIN per vec-slot (pass 1)

        // ---- two sweeps: pass 0 = find true approx min; pass 1 = collect ----
#pragma unroll 1
        for (int pass = 0; pass < 2; ++pass) {
            FETCH(0);
            WRITE(0);
            float runmin[2] = { INFINITY, INFINITY };
            f32x16 acc[2];
#pragma unroll
            for (int tc = 0; tc < 2; ++tc)
#pragma unroll
                for (int j = 0; j < 16; ++j) acc[tc][j] = 0.f;
            __syncthreads();

            int cur = 0;
#pragma unroll 1
            for (int ch = 0; ch < NCHUNK; ++ch) {
                bool pf = (ch + 1 < NCHUNK);
                if (pf) FETCH(ch + 1);  // loads in flight under compute
                const int cbase = ch * CHUNK + cg * 32;
                float4 cnq[4];
#pragma unroll
                for (int q = 0; q < 4; ++q)
                    cnq[q] = *(const float4*)&s_cnorm[cbase + 4 * h + 8 * q];
#pragma unroll
                for (int ks = 0; ks < 8; ++ks) {
                    bf16x8 a = *(const bf16x8*)&sA[cur][((cg * 8 + ks) * 64 + l) * 8];
                    acc[0] = __builtin_amdgcn_mfma_f32_32x32x16_bf16(a, breg[0][ks], acc[0], 0, 0, 0);
                    acc[1] = __builtin_amdgcn_mfma_f32_32x32x16_bf16(a, breg[1][ks], acc[1], 0, 0, 0);
                }
                if (pass == 0) {
#pragma unroll
                    for (int tc = 0; tc < 2; ++tc)
#pragma unroll
                        for (int r = 0; r < 16; ++r) {
                            float sc = fmaf(acc[tc][r], -2.f, cnq[r >> 2][r & 3]);
                            runmin[tc] = fminf(runmin[tc], sc);
                            acc[tc][r] = 0.f;
                        }
                } else {
#pragma unroll
                    for (int tc = 0; tc < 2; ++tc) {
                        int vl = vg * 64 + tc * 32 + l31;
#pragma unroll
                        for (int r = 0; r < 16; ++r) {
                            float sc = fmaf(acc[tc][r], -2.f, cnq[r >> 2][r & 3]);
                            if (sc <= vthr[tc]) {
                                int code = cbase + (r & 3) + 8 * (r >> 2) + 4 * h;
                                int o = atomicAdd(&s_cnt[vl], 1);
                                if (o < CAP) s_cand[vl * CAP + o] = (unsigned short)code;
                                else s_ovf[vl] = 1;
                            }
                            acc[tc][r] = 0.f;
                        }
                    }
                }
                if (pf) WRITE(cur ^ 1);
                __syncthreads();
                cur ^= 1;
            }

            if (pass == 0) {
                // reduce the 4 holders (2 waves x 2 halves) of each vector
#pragma unroll
                for (int tc = 0; tc < 2; ++tc)
                    atomicMin(&s_vmin[vg * 64 + tc * 32 + l31], fmap(runmin[tc]));
                __syncthreads();
#pragma unroll
                for (int tc = 0; tc < 2; ++tc)
                    vthr[tc] = funmap(s_vmin[vg * 64 + tc * 32 + l31]) + MARGIN;
            }
        }

        // ---- exact fp32 re-rank (bit-matches numpy; round-1-verified recipe) ----
        if (tid < BM && !s_ovf[tid]) {
            int n = s_cnt[tid];
            int bidx = 0;
            if (n == 1) {
                bidx = s_cand[tid * CAP];
            } else if (n > 1) {
                unsigned short* cl = &s_cand[tid * CAP];
                for (int a = 1; a < n; ++a) {          // sort ascending (determinism)
                    unsigned short key = cl[a];
                    int b = a - 1;
                    while (b >= 0 && cl[b] > key) { cl[b + 1] = cl[b]; --b; }
                    cl[b + 1] = key;
                }
                const float* rv = rsrc + (size_t)tid * DIM;
                float rn = np_pairwise_sq128(rv);
                float best = INFINITY;
                for (int k = 0; k < n; ++k) {
                    int c = cl[k];
                    const float* cp = cb + ((size_t)s * NC + c) * DIM;
                    float a0 = 0.f;
                    for (int d = 0; d < DIM; ++d)
                        a0 = __builtin_fmaf(rv[d], cp[d], a0);
                    float dist = (rn + s_cnorm[c]) - 2.0f * a0;
                    if (dist < best) { best = dist; bidx = c; }  // strict <, ascending c
                }
            }
            s_idx[tid] = bidx;
        }
        __syncthreads();
        if (tid < BM && s_ovf[tid]) {
            int p = atomicAdd(&s_ovn, 1);
            s_ovlist[p] = tid;
        }
        __syncthreads();
        // rare overflow: wave-parallel exact scan over all 1024 codes
        for (int o = w; o < s_ovn; o += 4) {
            int vec = s_ovlist[o];
            const float* rv = rsrc + (size_t)vec * DIM;
            float rn = np_pairwise_sq128(rv);
            float best = INFINITY; int bidx = 0;
            for (int k = 0; k < 16; ++k) {
                int c = k * 64 + l;  // ascending within lane
                const float* cp = cb + ((size_t)s * NC + c) * DIM;
                float a0 = 0.f;
                for (int d = 0; d < DIM; ++d)
                    a0 = __builtin_fmaf(rv[d], cp[d], a0);
                float dist = (rn + s_cnorm[c]) - 2.0f * a0;
                if (dist < best) { best = dist; bidx = c; }
            }
#pragma unroll
            for (int off = 32; off >= 1; off >>= 1) {  // lexicographic (dist, idx) min
                float ob = __shfl_xor(best, off, 64);
                int oi = __shfl_xor(bidx, off, 64);
                if (ob < best || (ob == best && oi < bidx)) { best = ob; bidx = oi; }
            }
            if (l == 0) s_idx[vec] = bidx;
        }
        __syncthreads();

        // ---- residual update (exact fp32, elementwise) + index write ----
        {
            int vec = tid >> 1;
            int d0 = (tid & 1) * 64;
            int c = s_idx[vec];
            const float* rv = rsrc + (size_t)vec * DIM + d0;
            const float* cp = cb + ((size_t)s * NC + c) * DIM + d0;
            float* ro = rbuf + (size_t)(blockbase + vec) * DIM + d0;
            if (s < NS - 1) {
#pragma unroll
                for (int i = 0; i < 64; i += 4) {
                    float4 rr = *(const float4*)(rv + i);
                    float4 cc = *(const float4*)(cp + i);
                    float4 oo;
                    oo.x = rr.x - cc.x; oo.y = rr.y - cc.y;
                    oo.z = rr.z - cc.z; oo.w = rr.w - cc.w;
                    *(float4*)(ro + i) = oo;
                }
            } else {  // last stage: q = x - r_new
                const float* xv = x + (size_t)(blockbase + vec) * DIM + d0;
#pragma unroll
                for (int i = 0; i < 64; i += 4) {
                    float4 rr = *(const float4*)(rv + i);
                    float4 cc = *(const float4*)(cp + i);
                    float4 xx = *(const float4*)(xv + i);
                    float4 oo;
                    oo.x = xx.x - (rr.x - cc.x); oo.y = xx.y - (rr.y - cc.y);
                    oo.z = xx.z - (rr.z - cc.z); oo.w = xx.w - (rr.w - cc.w);
                    *(float4*)(ro + i) = oo;
                }
            }
            if (tid < BM)
                out[QSIZE + (size_t)s * NVEC + blockbase + tid] = (float)s_idx[tid];
        }
        __syncthreads();
    }
#undef FETCH
#undef WRITE
}

extern "C" void kernel_launch(void* const* d_in, const int* in_sizes, int n_in,
                              void* d_out, int out_size, void* d_ws, size_t ws_size,
                              hipStream_t stream) {
    const float* x  = (const float*)d_in[0];   // [16, 8192, 128] fp32
    const float* cb = (const float*)d_in[1];   // [4, 1024, 128] fp32
    short* cb_bf = (short*)d_ws;                                   // 1 MB
    float* cnorm = (float*)((char*)d_ws + (size_t)NS * NC * DIM * sizeof(short));
    float* out = (float*)d_out;

    rvq_prologue<<<(NS * NC + 255) / 256, 256, 0, stream>>>(cb, cb_bf, cnorm);
    rvq_main<<<NVEC / BM, 256, 0, stream>>>(x, cb, cb_bf, cnorm, out);
}

// Round 4
// 930.999 us; speedup vs baseline: 20.8963x; 1.0471x over previous
//
#include <hip/hip_runtime.h>
#include <hip/hip_bf16.h>
#include <math.h>

constexpr int DIM = 128;
constexpr int NC = 1024;
constexpr int NS = 4;
constexpr int NVEC = 16 * 8192;
constexpr size_t QSIZE = (size_t)NVEC * DIM;
constexpr int BM = 64;             // vectors per block
constexpr int CAP = 12;            // candidate capacity per vector
constexpr float MARGIN = 0.125f;   // >= 2 * worst-case bf16 score error (~0.044)
constexpr int RS = DIM + 1;        // 129: padded LDS residual row stride (floats)

typedef short bf16x8 __attribute__((ext_vector_type(8)));
typedef float f32x16 __attribute__((ext_vector_type(16)));

__device__ __forceinline__ short f2bf(float f) {
    __hip_bfloat16 h = __float2bfloat16(f);
    union { __hip_bfloat16 h; short s; } u;
    u.h = h;
    return u.s;
}

// Order-preserving float->uint map (for LDS atomicMin on signed scores).
__device__ __forceinline__ unsigned fmap(float f) {
    unsigned u = __float_as_uint(f);
    return (u & 0x80000000u) ? ~u : (u | 0x80000000u);
}
__device__ __forceinline__ float funmap(unsigned k) {
    unsigned u = (k & 0x80000000u) ? (k & 0x7FFFFFFFu) : ~k;
    return __uint_as_float(u);
}

// numpy pairwise sum of squares for exactly 128 elements (8 stride-8 accums,
// tree combine, squares rounded separately).
template <typename PTR>
__device__ __forceinline__ float np_pairwise_sq128(PTR v) {
#pragma clang fp contract(off)
    float r[8];
#pragma unroll
    for (int j = 0; j < 8; ++j) { float sq = v[j] * v[j]; r[j] = sq; }
#pragma unroll
    for (int i = 8; i < DIM; i += 8) {
#pragma unroll
        for (int j = 0; j < 8; ++j) { float sq = v[i + j] * v[i + j]; r[j] = r[j] + sq; }
    }
    return ((r[0] + r[1]) + (r[2] + r[3])) + ((r[4] + r[5]) + (r[6] + r[7]));
}

// Prologue: exact fp32 code norms + bf16 copies of the codebooks.
__global__ __launch_bounds__(256) void rvq_prologue(
        const float* __restrict__ cb, short* __restrict__ cb_bf,
        float* __restrict__ cnorm) {
    int row = blockIdx.x * 256 + threadIdx.x;
    if (row >= NS * NC) return;
    const float* src = cb + (size_t)row * DIM;
    cnorm[row] = np_pairwise_sq128(src);
    short* dst = cb_bf + (size_t)row * DIM;
    for (int i = 0; i < DIM; ++i) dst[i] = f2bf(src[i]);
}

__global__ __launch_bounds__(256, 3) void rvq_main(
        const float* __restrict__ x,
        const float* __restrict__ cb,       // fp32 codebooks (exact path)
        const short* __restrict__ cb_bf,    // bf16 codebooks (MFMA path)
        const float* __restrict__ cnorm_ws, // exact code norms
        float* __restrict__ out) {
    __shared__ float s_res[BM * RS];            // 33KB: fp32 residuals, +1 pad
    __shared__ float s_cnorm[NC];               // 4KB
    __shared__ unsigned s_vmin[BM];
    __shared__ unsigned short s_cand[BM * CAP];
    __shared__ int s_cnt[BM];
    __shared__ int s_ovf[BM];
    __shared__ int s_idx[BM];
    __shared__ int s_ovlist[BM];
    __shared__ int s_ovn;

    const int tid = threadIdx.x;
    const int w = tid >> 6;      // wave 0..3: owns codes [w*256, w*256+256)
    const int l = tid & 63;
    const int l31 = l & 31;
    const int h = l >> 5;
    const int Q = w * 256;
    const int blockbase = blockIdx.x * BM;

    // ---- init: residual = x (coalesced global, scalar LDS writes) ----
    for (int i4 = tid; i4 < BM * DIM / 4; i4 += 256) {
        int vec = i4 >> 5, d4 = (i4 & 31) * 4;
        float4 t = *(const float4*)(x + (size_t)(blockbase + vec) * DIM + d4);
        float* rp = &s_res[vec * RS + d4];
        rp[0] = t.x; rp[1] = t.y; rp[2] = t.z; rp[3] = t.w;
    }

#pragma unroll 1
    for (int s = 0; s < NS; ++s) {
        // ---- stage setup ----
        for (int i = tid; i < NC; i += 256) s_cnorm[i] = cnorm_ws[s * NC + i];
        if (tid < BM) { s_cnt[tid] = 0; s_ovf[tid] = 0; s_vmin[tid] = 0xFFFFFFFFu; }
        if (tid == 0) s_ovn = 0;
        __syncthreads();   // also covers: previous stage's residual update done

        // B fragments from LDS residual (scalar reads, conflict-free), packed
        // once per stage, reused by both passes. Same assumed k-map as the
        // direct A loads -> k-layout errors cancel (round-3-verified).
        bf16x8 breg[2][8];
#pragma unroll
        for (int tc = 0; tc < 2; ++tc) {
            const float* p = &s_res[(tc * 32 + l31) * RS + h * 8];
#pragma unroll
            for (int ks = 0; ks < 8; ++ks) {
                bf16x8 b;
#pragma unroll
                for (int j = 0; j < 8; ++j) b[j] = f2bf(p[ks * 16 + j]);
                breg[tc][ks] = b;
            }
        }

        const short* cbbf_s = cb_bf + (size_t)s * NC * DIM;
        float vthr[2];
        float runmin[2] = { INFINITY, INFINITY };

        // ---- two barrier-free sweeps over this wave's 256 codes ----
#pragma unroll 1
        for (int pass = 0; pass < 2; ++pass) {
#pragma unroll 2
            for (int sub = 0; sub < 8; ++sub) {
                const int cbase = Q + sub * 32;
                // A-fragments direct from global (L2-resident codebook):
                // lane -> code row cbase+l31, bytes ks*32 + h*16.
                const short* ap = cbbf_s + (size_t)(cbase + l31) * DIM + h * 8;
                f32x16 acc0, acc1;
#pragma unroll
                for (int j = 0; j < 16; ++j) { acc0[j] = 0.f; acc1[j] = 0.f; }
#pragma unroll
                for (int ks = 0; ks < 8; ++ks) {
                    bf16x8 a = *(const bf16x8*)(ap + ks * 16);
                    acc0 = __builtin_amdgcn_mfma_f32_32x32x16_bf16(a, breg[0][ks], acc0, 0, 0, 0);
                    acc1 = __builtin_amdgcn_mfma_f32_32x32x16_bf16(a, breg[1][ks], acc1, 0, 0, 0);
                }
                float4 cnq[4];
#pragma unroll
                for (int q = 0; q < 4; ++q)
                    cnq[q] = *(const float4*)&s_cnorm[cbase + 4 * h + 8 * q];
                if (pass == 0) {
#pragma unroll
                    for (int r = 0; r < 16; ++r) {
                        float sc0 = fmaf(acc0[r], -2.f, cnq[r >> 2][r & 3]);
                        float sc1 = fmaf(acc1[r], -2.f, cnq[r >> 2][r & 3]);
                        runmin[0] = fminf(runmin[0], sc0);
                        runmin[1] = fminf(runmin[1], sc1);
                    }
                } else {
#pragma unroll
                    for (int r = 0; r < 16; ++r) {
                        float sc0 = fmaf(acc0[r], -2.f, cnq[r >> 2][r & 3]);
                        float sc1 = fmaf(acc1[r], -2.f, cnq[r >> 2][r & 3]);
                        int code = cbase + (r & 3) + 8 * (r >> 2) + 4 * h;
                        if (sc0 <= vthr[0]) {
                            int o = atomicAdd(&s_cnt[l31], 1);
                            if (o < CAP) s_cand[l31 * CAP + o] = (unsigned short)code;
                            else s_ovf[l31] = 1;
                        }
                        if (sc1 <= vthr[1]) {
                            int o = atomicAdd(&s_cnt[32 + l31], 1);
                            if (o < CAP) s_cand[(32 + l31) * CAP + o] = (unsigned short)code;
                            else s_ovf[32 + l31] = 1;
                        }
                    }
                }
            }
            if (pass == 0) {
                atomicMin(&s_vmin[l31], fmap(runmin[0]));
                atomicMin(&s_vmin[32 + l31], fmap(runmin[1]));
                __syncthreads();
                vthr[0] = funmap(s_vmin[l31]) + MARGIN;
                vthr[1] = funmap(s_vmin[32 + l31]) + MARGIN;
            }
        }
        __syncthreads();

        // ---- exact fp32 re-rank (bit-matches numpy; round-1-verified recipe) ----
        if (tid < BM && !s_ovf[tid]) {
            int n = s_cnt[tid];
            int bidx = 0;
            if (n == 1) {
                bidx = s_cand[tid * CAP];
            } else if (n > 1) {
                unsigned short* cl = &s_cand[tid * CAP];
                for (int a = 1; a < n; ++a) {          // sort ascending (determinism)
                    unsigned short key = cl[a];
                    int b = a - 1;
                    while (b >= 0 && cl[b] > key) { cl[b + 1] = cl[b]; --b; }
                    cl[b + 1] = key;
                }
                const float* rv = &s_res[tid * RS];
                float rn = np_pairwise_sq128(rv);
                float best = INFINITY;
                for (int k = 0; k < n; ++k) {
                    int c = cl[k];
                    const float* cp = cb + ((size_t)s * NC + c) * DIM;
                    float a0 = 0.f;
                    for (int d = 0; d < DIM; ++d)
                        a0 = __builtin_fmaf(rv[d], cp[d], a0);
                    float dist = (rn + s_cnorm[c]) - 2.0f * a0;
                    if (dist < best) { best = dist; bidx = c; }  // strict <, ascending c
                }
            }
            s_idx[tid] = bidx;
        }
        __syncthreads();
        if (tid < BM && s_ovf[tid]) {
            int p = atomicAdd(&s_ovn, 1);
            s_ovlist[p] = tid;
        }
        __syncthreads();
        // rare overflow: wave-parallel exact scan over all 1024 codes
        for (int o = w; o < s_ovn; o += 4) {
            int vec = s_ovlist[o];
            const float* rv = &s_res[vec * RS];
            float rn = np_pairwise_sq128(rv);
            float best = INFINITY; int bidx = 0;
            for (int k = 0; k < 16; ++k) {
                int c = k * 64 + l;  // ascending within lane
                const float* cp = cb + ((size_t)s * NC + c) * DIM;
                float a0 = 0.f;
                for (int d = 0; d < DIM; ++d)
                    a0 = __builtin_fmaf(rv[d], cp[d], a0);
                float dist = (rn + s_cnorm[c]) - 2.0f * a0;
                if (dist < best) { best = dist; bidx = c; }
            }
#pragma unroll
            for (int off = 32; off >= 1; off >>= 1) {  // lexicographic (dist, idx) min
                float ob = __shfl_xor(best, off, 64);
                int oi = __shfl_xor(bidx, off, 64);
                if (ob < best || (ob == best && oi < bidx)) { best = ob; bidx = oi; }
            }
            if (l == 0) s_idx[vec] = bidx;
        }
        __syncthreads();

        // ---- residual update in LDS (exact fp32) / final q write ----
        if (s < NS - 1) {
            for (int i4 = tid; i4 < BM * DIM / 4; i4 += 256) {
                int vec = i4 >> 5, d4 = (i4 & 31) * 4;
                int c = s_idx[vec];
                float4 cc = *(const float4*)(cb + ((size_t)s * NC + c) * DIM + d4);
                float* rp = &s_res[vec * RS + d4];
                rp[0] = rp[0] - cc.x; rp[1] = rp[1] - cc.y;
                rp[2] = rp[2] - cc.z; rp[3] = rp[3] - cc.w;
            }
        } else {  // q = x - (r - chosen), exact round-3 expression
            for (int i4 = tid; i4 < BM * DIM / 4; i4 += 256) {
                int vec = i4 >> 5, d4 = (i4 & 31) * 4;
                int c = s_idx[vec];
                float4 cc = *(const float4*)(cb + ((size_t)s * NC + c) * DIM + d4);
                float4 xx = *(const float4*)(x + (size_t)(blockbase + vec) * DIM + d4);
                const float* rp = &s_res[vec * RS + d4];
                float4 oo;
                oo.x = xx.x - (rp[0] - cc.x); oo.y = xx.y - (rp[1] - cc.y);
                oo.z = xx.z - (rp[2] - cc.z); oo.w = xx.w - (rp[3] - cc.w);
                *(float4*)(out + (size_t)(blockbase + vec) * DIM + d4) = oo;
            }
        }
        if (tid < BM)
            out[QSIZE + (size_t)s * NVEC + blockbase + tid] = (float)s_idx[tid];
        __syncthreads();
    }
}

extern "C" void kernel_launch(void* const* d_in, const int* in_sizes, int n_in,
                              void* d_out, int out_size, void* d_ws, size_t ws_size,
                              hipStream_t stream) {
    const float* x  = (const float*)d_in[0];   // [16, 8192, 128] fp32
    const float* cb = (const float*)d_in[1];   // [4, 1024, 128] fp32
    short* cb_bf = (short*)d_ws;                                   // 1 MB
    float* cnorm = (float*)((char*)d_ws + (size_t)NS * NC * DIM * sizeof(short));
    float* out = (float*)d_out;

    rvq_prologue<<<(NS * NC + 255) / 256, 256, 0, stream>>>(cb, cb_bf, cnorm);
    rvq_main<<<NVEC / BM, 256, 0, stream>>>(x, cb, cb_bf, cnorm, out);
}

// Round 5
// 765.390 us; speedup vs baseline: 25.4177x; 1.2164x over previous
//
#include <hip/hip_runtime.h>
#include <hip/hip_bf16.h>
#include <math.h>

constexpr int DIM = 128;
constexpr int NC = 1024;
constexpr int NS = 4;
constexpr int NVEC = 16 * 8192;
constexpr size_t QSIZE = (size_t)NVEC * DIM;
constexpr int BM = 64;             // vectors per block
constexpr int CAP = 32;            // candidate capacity per vector
constexpr float MARGIN = 0.125f;   // >= 2 * worst-case bf16 score error (~0.044)
constexpr int RS = DIM + 1;        // 129: padded LDS residual row stride (floats)

typedef short bf16x8 __attribute__((ext_vector_type(8)));
typedef float f32x16 __attribute__((ext_vector_type(16)));

__device__ __forceinline__ short f2bf(float f) {
    __hip_bfloat16 h = __float2bfloat16(f);
    union { __hip_bfloat16 h; short s; } u;
    u.h = h;
    return u.s;
}

// Branchless round-to-nearest-even f32->bf16 (== RNE for all finite values;
// inputs here are finite). Used in the per-stage breg pack.
__device__ __forceinline__ short f2bf_fast(float f) {
    unsigned u = __float_as_uint(f);
    unsigned r = (u + 0x7FFFu + ((u >> 16) & 1u)) >> 16;
    return (short)r;
}

// Order-preserving float->uint map (for LDS atomicMin on signed scores).
__device__ __forceinline__ unsigned fmap(float f) {
    unsigned u = __float_as_uint(f);
    return (u & 0x80000000u) ? ~u : (u | 0x80000000u);
}
__device__ __forceinline__ float funmap(unsigned k) {
    unsigned u = (k & 0x80000000u) ? (k & 0x7FFFFFFFu) : ~k;
    return __uint_as_float(u);
}

// numpy pairwise sum of squares for exactly 128 elements (8 stride-8 accums,
// tree combine, squares rounded separately).
template <typename PTR>
__device__ __forceinline__ float np_pairwise_sq128(PTR v) {
#pragma clang fp contract(off)
    float r[8];
#pragma unroll
    for (int j = 0; j < 8; ++j) { float sq = v[j] * v[j]; r[j] = sq; }
#pragma unroll
    for (int i = 8; i < DIM; i += 8) {
#pragma unroll
        for (int j = 0; j < 8; ++j) { float sq = v[i + j] * v[i + j]; r[j] = r[j] + sq; }
    }
    return ((r[0] + r[1]) + (r[2] + r[3])) + ((r[4] + r[5]) + (r[6] + r[7]));
}

// Exact numpy-recipe distance for one (residual,row) pair: sequential fmaf
// chain over d ascending, float4 loads (same bits as scalar: components
// consumed in order), dist = (rn + cnorm) - 2*dot.
__device__ __forceinline__ float exact_dist(const float* __restrict__ rv,
                                            const float* __restrict__ cp,
                                            float rn, float cn) {
    float a0 = 0.f;
#pragma unroll
    for (int d = 0; d < DIM; d += 4) {
        float4 q = *(const float4*)(cp + d);
        a0 = __builtin_fmaf(rv[d], q.x, a0);
        a0 = __builtin_fmaf(rv[d + 1], q.y, a0);
        a0 = __builtin_fmaf(rv[d + 2], q.z, a0);
        a0 = __builtin_fmaf(rv[d + 3], q.w, a0);
    }
    return (rn + cn) - 2.0f * a0;
}

// Prologue: exact fp32 code norms + bf16 copies of the codebooks.
__global__ __launch_bounds__(256) void rvq_prologue(
        const float* __restrict__ cb, short* __restrict__ cb_bf,
        float* __restrict__ cnorm) {
    int row = blockIdx.x * 256 + threadIdx.x;
    if (row >= NS * NC) return;
    const float* src = cb + (size_t)row * DIM;
    cnorm[row] = np_pairwise_sq128(src);
    short* dst = cb_bf + (size_t)row * DIM;
    for (int i = 0; i < DIM; ++i) dst[i] = f2bf(src[i]);
}

__global__ __launch_bounds__(256, 3) void rvq_main(
        const float* __restrict__ x,
        const float* __restrict__ cb,       // fp32 codebooks (exact path)
        const short* __restrict__ cb_bf,    // bf16 codebooks (MFMA path)
        const float* __restrict__ cnorm_ws, // exact code norms
        float* __restrict__ out) {
    __shared__ float s_res[BM * RS];            // 33KB: fp32 residuals, +1 pad
    __shared__ float s_cnorm[NC];               // 4KB
    __shared__ unsigned s_vmin[BM];
    __shared__ unsigned short s_cand[BM * CAP]; // 4KB
    __shared__ unsigned long long s_best[BM];   // packed (dist,idx) min
    __shared__ float s_rn[BM];
    __shared__ int s_cnt[BM];
    __shared__ int s_ovf[BM];
    __shared__ int s_idx[BM];
    __shared__ int s_ovlist[BM];
    __shared__ int s_ovn;

    const int tid = threadIdx.x;
    const int w = tid >> 6;      // wave 0..3: owns codes [w*256, w*256+256)
    const int l = tid & 63;
    const int l31 = l & 31;
    const int h = l >> 5;
    const int Q = w * 256;
    const int blockbase = blockIdx.x * BM;

    // ---- init: residual = x (coalesced global, scalar LDS writes) ----
    for (int i4 = tid; i4 < BM * DIM / 4; i4 += 256) {
        int vec = i4 >> 5, d4 = (i4 & 31) * 4;
        float4 t = *(const float4*)(x + (size_t)(blockbase + vec) * DIM + d4);
        float* rp = &s_res[vec * RS + d4];
        rp[0] = t.x; rp[1] = t.y; rp[2] = t.z; rp[3] = t.w;
    }

#pragma unroll 1
    for (int s = 0; s < NS; ++s) {
        // ---- stage setup ----
        for (int i = tid; i < NC; i += 256) s_cnorm[i] = cnorm_ws[s * NC + i];
        if (tid < BM) {
            s_cnt[tid] = 0; s_ovf[tid] = 0; s_vmin[tid] = 0xFFFFFFFFu;
            s_best[tid] = ~0ull;
        }
        if (tid == 0) s_ovn = 0;
        __syncthreads();   // also covers: previous stage's residual update done

        // Per-vector exact residual norm (numpy recipe), once per stage.
        if (tid < BM) s_rn[tid] = np_pairwise_sq128(&s_res[tid * RS]);

        // B fragments from LDS residual (scalar reads, conflict-free), packed
        // once per stage, reused by both passes. Same assumed k-map as the
        // direct A loads -> k-layout errors cancel (round-3-verified).
        bf16x8 breg[2][8];
#pragma unroll
        for (int tc = 0; tc < 2; ++tc) {
            const float* p = &s_res[(tc * 32 + l31) * RS + h * 8];
#pragma unroll
            for (int ks = 0; ks < 8; ++ks) {
                bf16x8 b;
#pragma unroll
                for (int j = 0; j < 8; ++j) b[j] = f2bf_fast(p[ks * 16 + j]);
                breg[tc][ks] = b;
            }
        }

        const short* cbbf_s = cb_bf + (size_t)s * NC * DIM;
        float vthr[2];
        float runmin[2] = { INFINITY, INFINITY };

        // ---- two barrier-free sweeps over this wave's 256 codes ----
#pragma unroll 1
        for (int pass = 0; pass < 2; ++pass) {
#pragma unroll 2
            for (int sub = 0; sub < 8; ++sub) {
                const int cbase = Q + sub * 32;
                // A-fragments direct from global (L2-resident codebook):
                // lane -> code row cbase+l31, bytes ks*32 + h*16.
                const short* ap = cbbf_s + (size_t)(cbase + l31) * DIM + h * 8;
                f32x16 acc0, acc1;
#pragma unroll
                for (int j = 0; j < 16; ++j) { acc0[j] = 0.f; acc1[j] = 0.f; }
#pragma unroll
                for (int ks = 0; ks < 8; ++ks) {
                    bf16x8 a = *(const bf16x8*)(ap + ks * 16);
                    acc0 = __builtin_amdgcn_mfma_f32_32x32x16_bf16(a, breg[0][ks], acc0, 0, 0, 0);
                    acc1 = __builtin_amdgcn_mfma_f32_32x32x16_bf16(a, breg[1][ks], acc1, 0, 0, 0);
                }
                float4 cnq[4];
#pragma unroll
                for (int q = 0; q < 4; ++q)
                    cnq[q] = *(const float4*)&s_cnorm[cbase + 4 * h + 8 * q];
                if (pass == 0) {
#pragma unroll
                    for (int r = 0; r < 16; ++r) {
                        float sc0 = fmaf(acc0[r], -2.f, cnq[r >> 2][r & 3]);
                        float sc1 = fmaf(acc1[r], -2.f, cnq[r >> 2][r & 3]);
                        runmin[0] = fminf(runmin[0], sc0);
                        runmin[1] = fminf(runmin[1], sc1);
                    }
                } else {
#pragma unroll
                    for (int r = 0; r < 16; ++r) {
                        float sc0 = fmaf(acc0[r], -2.f, cnq[r >> 2][r & 3]);
                        float sc1 = fmaf(acc1[r], -2.f, cnq[r >> 2][r & 3]);
                        int code = cbase + (r & 3) + 8 * (r >> 2) + 4 * h;
                        if (sc0 <= vthr[0]) {
                            int o = atomicAdd(&s_cnt[l31], 1);
                            if (o < CAP) s_cand[l31 * CAP + o] = (unsigned short)code;
                            else s_ovf[l31] = 1;
                        }
                        if (sc1 <= vthr[1]) {
                            int o = atomicAdd(&s_cnt[32 + l31], 1);
                            if (o < CAP) s_cand[(32 + l31) * CAP + o] = (unsigned short)code;
                            else s_ovf[32 + l31] = 1;
                        }
                    }
                }
            }
            if (pass == 0) {
                atomicMin(&s_vmin[l31], fmap(runmin[0]));
                atomicMin(&s_vmin[32 + l31], fmap(runmin[1]));
                __syncthreads();
                vthr[0] = funmap(s_vmin[l31]) + MARGIN;
                vthr[1] = funmap(s_vmin[32 + l31]) + MARGIN;
            }
        }
        __syncthreads();

        // ---- exact fp32 re-rank, candidate-parallel across the 4 waves ----
        // Candidate k of vector v is evaluated by wave (k&3); results combine
        // via u64 atomicMin on pack = fmap(dist)<<32 | code — lexicographic
        // (dist, idx) min == numpy first-occurrence argmin. Order-independent
        // => deterministic despite unordered candidate append.
        {
            int vec = l;  // each wave covers all 64 vectors
            int n = s_cnt[vec];
            if (!s_ovf[vec]) {
                if (n == 1) {
                    if (w == 0) s_idx[vec] = s_cand[vec * CAP];
                } else {
                    const float* rv = &s_res[vec * RS];
                    float rn = s_rn[vec];
                    for (int k = w; k < n; k += 4) {
                        int c = s_cand[vec * CAP + k];
                        float dist = exact_dist(rv, cb + ((size_t)s * NC + c) * DIM,
                                                rn, s_cnorm[c]);
                        unsigned long long pack =
                            ((unsigned long long)fmap(dist) << 32) | (unsigned)c;
                        atomicMin(&s_best[vec], pack);
                    }
                }
            }
        }
        __syncthreads();
        if (tid < BM && !s_ovf[tid] && s_cnt[tid] > 1)
            s_idx[tid] = (int)(unsigned)(s_best[tid] & 0xFFFFFFFFull);
        if (tid < BM && s_ovf[tid]) {
            int p = atomicAdd(&s_ovn, 1);
            s_ovlist[p] = tid;
        }
        __syncthreads();
        // rare overflow: wave-parallel exact scan over all 1024 codes
        for (int o = w; o < s_ovn; o += 4) {
            int vec = s_ovlist[o];
            const float* rv = &s_res[vec * RS];
            float rn = s_rn[vec];
            float best = INFINITY; int bidx = 0;
            for (int k = 0; k < 16; ++k) {
                int c = k * 64 + l;  // ascending within lane
                float dist = exact_dist(rv, cb + ((size_t)s * NC + c) * DIM,
                                        rn, s_cnorm[c]);
                if (dist < best) { best = dist; bidx = c; }
            }
#pragma unroll
            for (int off = 32; off >= 1; off >>= 1) {  // lexicographic (dist, idx) min
                float ob = __shfl_xor(best, off, 64);
                int oi = __shfl_xor(bidx, off, 64);
                if (ob < best || (ob == best && oi < bidx)) { best = ob; bidx = oi; }
            }
            if (l == 0) s_idx[vec] = bidx;
        }
        __syncthreads();

        // ---- residual update in LDS (exact fp32) / final q write ----
        if (s < NS - 1) {
            for (int i4 = tid; i4 < BM * DIM / 4; i4 += 256) {
                int vec = i4 >> 5, d4 = (i4 & 31) * 4;
                int c = s_idx[vec];
                float4 cc = *(const float4*)(cb + ((size_t)s * NC + c) * DIM + d4);
                float* rp = &s_res[vec * RS + d4];
                rp[0] = rp[0] - cc.x; rp[1] = rp[1] - cc.y;
                rp[2] = rp[2] - cc.z; rp[3] = rp[3] - cc.w;
            }
        } else {  // q = x - (r - chosen), exact round-3 expression
            for (int i4 = tid; i4 < BM * DIM / 4; i4 += 256) {
                int vec = i4 >> 5, d4 = (i4 & 31) * 4;
                int c = s_idx[vec];
                float4 cc = *(const float4*)(cb + ((size_t)s * NC + c) * DIM + d4);
                float4 xx = *(const float4*)(x + (size_t)(blockbase + vec) * DIM + d4);
                const float* rp = &s_res[vec * RS + d4];
                float4 oo;
                oo.x = xx.x - (rp[0] - cc.x); oo.y = xx.y - (rp[1] - cc.y);
                oo.z = xx.z - (rp[2] - cc.z); oo.w = xx.w - (rp[3] - cc.w);
                *(float4*)(out + (size_t)(blockbase + vec) * DIM + d4) = oo;
            }
        }
        if (tid < BM)
            out[QSIZE + (size_t)s * NVEC + blockbase + tid] = (float)s_idx[tid];
        __syncthreads();
    }
}

extern "C" void kernel_launch(void* const* d_in, const int* in_sizes, int n_in,
                              void* d_out, int out_size, void* d_ws, size_t ws_size,
                              hipStream_t stream) {
    const float* x  = (const float*)d_in[0];   // [16, 8192, 128] fp32
    const float* cb = (const float*)d_in[1];   // [4, 1024, 128] fp32
    short* cb_bf = (short*)d_ws;                                   // 1 MB
    float* cnorm = (float*)((char*)d_ws + (size_t)NS * NC * DIM * sizeof(short));
    float* out = (float*)d_out;

    rvq_prologue<<<(NS * NC + 255) / 256, 256, 0, stream>>>(cb, cb_bf, cnorm);
    rvq_main<<<NVEC / BM, 256, 0, stream>>>(x, cb, cb_bf, cnorm, out);
}

// Round 6
// 566.072 us; speedup vs baseline: 34.3675x; 1.3521x over previous
//
#include <hip/hip_runtime.h>
#include <hip/hip_bf16.h>
#include <math.h>

constexpr int DIM = 128;
constexpr int NC = 1024;
constexpr int NS = 4;
constexpr int NVEC = 16 * 8192;
constexpr size_t QSIZE = (size_t)NVEC * DIM;
constexpr int BM = 64;             // vectors per block
constexpr int CAP = 32;            // candidate capacity per vector
constexpr float MARGIN = 0.125f;   // >= 2 * worst-case bf16 score error (~0.044)
constexpr int RS = DIM + 1;        // 129: padded LDS residual row stride (floats)
constexpr int GSZ = 8 * 64 * 8;    // 4096 bf16 per swizzled 32-code group

typedef short bf16x8 __attribute__((ext_vector_type(8)));
typedef float f32x16 __attribute__((ext_vector_type(16)));

__device__ __forceinline__ short f2bf(float f) {
    __hip_bfloat16 h = __float2bfloat16(f);
    union { __hip_bfloat16 h; short s; } u;
    u.h = h;
    return u.s;
}

// Branchless RNE f32->bf16 (== f2bf for all finite values).
__device__ __forceinline__ short f2bf_fast(float f) {
    unsigned u = __float_as_uint(f);
    unsigned r = (u + 0x7FFFu + ((u >> 16) & 1u)) >> 16;
    return (short)r;
}

// Order-preserving float->uint map (for LDS atomicMin on signed scores).
__device__ __forceinline__ unsigned fmap(float f) {
    unsigned u = __float_as_uint(f);
    return (u & 0x80000000u) ? ~u : (u | 0x80000000u);
}
__device__ __forceinline__ float funmap(unsigned k) {
    unsigned u = (k & 0x80000000u) ? (k & 0x7FFFFFFFu) : ~k;
    return __uint_as_float(u);
}

// numpy pairwise sum of squares for exactly 128 elements (8 stride-8 accums,
// tree combine, squares rounded separately).
template <typename PTR>
__device__ __forceinline__ float np_pairwise_sq128(PTR v) {
#pragma clang fp contract(off)
    float r[8];
#pragma unroll
    for (int j = 0; j < 8; ++j) { float sq = v[j] * v[j]; r[j] = sq; }
#pragma unroll
    for (int i = 8; i < DIM; i += 8) {
#pragma unroll
        for (int j = 0; j < 8; ++j) { float sq = v[i + j] * v[i + j]; r[j] = r[j] + sq; }
    }
    return ((r[0] + r[1]) + (r[2] + r[3])) + ((r[4] + r[5]) + (r[6] + r[7]));
}

// Exact numpy-recipe distance: sequential fmaf chain over d ascending,
// float4 loads (components consumed in order -> same bits as scalar).
__device__ __forceinline__ float exact_dist(const float* __restrict__ rv,
                                            const float* __restrict__ cp,
                                            float rn, float cn) {
    float a0 = 0.f;
#pragma unroll
    for (int d = 0; d < DIM; d += 4) {
        float4 q = *(const float4*)(cp + d);
        a0 = __builtin_fmaf(rv[d], q.x, a0);
        a0 = __builtin_fmaf(rv[d + 1], q.y, a0);
        a0 = __builtin_fmaf(rv[d + 2], q.z, a0);
        a0 = __builtin_fmaf(rv[d + 3], q.w, a0);
    }
    return (rn + cn) - 2.0f * a0;
}

// Prologue A: exact fp32 code norms (numpy recipe).
__global__ __launch_bounds__(256) void rvq_norms(
        const float* __restrict__ cb, float* __restrict__ cnorm) {
    int row = blockIdx.x * 256 + threadIdx.x;
    if (row >= NS * NC) return;
    cnorm[row] = np_pairwise_sq128(cb + (size_t)row * DIM);
}

// Prologue B: swizzle codebook into fragment-linear bf16 layout.
// swz[s][g][ks][l][j] = f2bf(cb[s][g*32 + (l&31)][ks*16 + (l>>5)*8 + j])
// => the sweep's A-load (ap + ks*512 + l*8) is lane-contiguous/coalesced and
// delivers bit-identical fragments to the previous divergent row loads.
__global__ __launch_bounds__(256) void rvq_swizzle(
        const float* __restrict__ cb, short* __restrict__ swz) {
    int bg = blockIdx.x;            // (s*32 + g), 128 blocks
    const float* src = cb + (size_t)bg * 32 * DIM;
    short* dst = swz + (size_t)bg * GSZ;
    int t = threadIdx.x;
#pragma unroll
    for (int i = 0; i < 2; ++i) {
        int o = t * 16 + i * 8;     // bf16 offset in group, multiple of 8
        int ks = o >> 9;
        int l = (o >> 3) & 63;
        const float* p = src + (l & 31) * DIM + ks * 16 + (l >> 5) * 8;
        bf16x8 v;
#pragma unroll
        for (int j = 0; j < 8; ++j) v[j] = f2bf(p[j]);
        *(bf16x8*)(dst + o) = v;
    }
}

__global__ __launch_bounds__(256, 3) void rvq_main(
        const float* __restrict__ x,
        const float* __restrict__ cb,       // fp32 codebooks (exact path)
        const short* __restrict__ swz,      // swizzled bf16 codebooks (MFMA path)
        const float* __restrict__ cnorm_ws, // exact code norms
        float* __restrict__ out) {
    __shared__ float s_res[BM * RS];            // 33KB: fp32 residuals, +1 pad
    __shared__ float s_cnorm[NC];               // 4KB
    __shared__ unsigned s_vmin[BM];
    __shared__ unsigned short s_cand[BM * CAP]; // 4KB
    __shared__ unsigned long long s_best[BM];   // packed (dist,idx) min
    __shared__ float s_rn[BM];
    __shared__ int s_cnt[BM];
    __shared__ int s_ovf[BM];
    __shared__ int s_idx[BM];
    __shared__ int s_ovlist[BM];
    __shared__ int s_ovn;

    const int tid = threadIdx.x;
    const int w = tid >> 6;      // wave 0..3: owns codes [w*256, w*256+256)
    const int l = tid & 63;
    const int l31 = l & 31;
    const int h = l >> 5;
    const int Q = w * 256;
    const int blockbase = blockIdx.x * BM;

    // ---- init: residual = x (coalesced global, scalar LDS writes) ----
    for (int i4 = tid; i4 < BM * DIM / 4; i4 += 256) {
        int vec = i4 >> 5, d4 = (i4 & 31) * 4;
        float4 t = *(const float4*)(x + (size_t)(blockbase + vec) * DIM + d4);
        float* rp = &s_res[vec * RS + d4];
        rp[0] = t.x; rp[1] = t.y; rp[2] = t.z; rp[3] = t.w;
    }

#pragma unroll 1
    for (int s = 0; s < NS; ++s) {
        // ---- stage setup ----
        for (int i = tid; i < NC; i += 256) s_cnorm[i] = cnorm_ws[s * NC + i];
        if (tid < BM) {
            s_cnt[tid] = 0; s_ovf[tid] = 0; s_vmin[tid] = 0xFFFFFFFFu;
            s_best[tid] = ~0ull;
        }
        if (tid == 0) s_ovn = 0;
        __syncthreads();   // also covers: previous stage's residual update done

        // Per-vector exact residual norm (numpy recipe), once per stage.
        if (tid < BM) s_rn[tid] = np_pairwise_sq128(&s_res[tid * RS]);

        // B fragments from LDS residual, packed once per stage, reused by both
        // passes. Same assumed k-map as the swizzled A layout -> k-layout
        // errors cancel (round-3-verified).
        bf16x8 breg[2][8];
#pragma unroll
        for (int tc = 0; tc < 2; ++tc) {
            const float* p = &s_res[(tc * 32 + l31) * RS + h * 8];
#pragma unroll
            for (int ks = 0; ks < 8; ++ks) {
                bf16x8 b;
#pragma unroll
                for (int j = 0; j < 8; ++j) b[j] = f2bf_fast(p[ks * 16 + j]);
                breg[tc][ks] = b;
            }
        }

        const short* swz_s = swz + (size_t)s * 32 * GSZ;
        float vthr[2];
        float runmin[2] = { INFINITY, INFINITY };

        // ---- two barrier-free sweeps over this wave's 256 codes ----
#pragma unroll 1
        for (int pass = 0; pass < 2; ++pass) {
#pragma unroll 2
            for (int sub = 0; sub < 8; ++sub) {
                const int cbase = Q + sub * 32;
                // Coalesced A-fragments: wave reads 1KB contiguous per ks.
                const short* ap = swz_s + (size_t)(w * 8 + sub) * GSZ;
                f32x16 acc0, acc1;
#pragma unroll
                for (int j = 0; j < 16; ++j) { acc0[j] = 0.f; acc1[j] = 0.f; }
#pragma unroll
                for (int ks = 0; ks < 8; ++ks) {
                    bf16x8 a = *(const bf16x8*)(ap + ks * 512 + l * 8);
                    acc0 = __builtin_amdgcn_mfma_f32_32x32x16_bf16(a, breg[0][ks], acc0, 0, 0, 0);
                    acc1 = __builtin_amdgcn_mfma_f32_32x32x16_bf16(a, breg[1][ks], acc1, 0, 0, 0);
                }
                float4 cnq[4];
#pragma unroll
                for (int q = 0; q < 4; ++q)
                    cnq[q] = *(const float4*)&s_cnorm[cbase + 4 * h + 8 * q];
                if (pass == 0) {
#pragma unroll
                    for (int r = 0; r < 16; ++r) {
                        float sc0 = fmaf(acc0[r], -2.f, cnq[r >> 2][r & 3]);
                        float sc1 = fmaf(acc1[r], -2.f, cnq[r >> 2][r & 3]);
                        runmin[0] = fminf(runmin[0], sc0);
                        runmin[1] = fminf(runmin[1], sc1);
                    }
                } else {
#pragma unroll
                    for (int r = 0; r < 16; ++r) {
                        float sc0 = fmaf(acc0[r], -2.f, cnq[r >> 2][r & 3]);
                        float sc1 = fmaf(acc1[r], -2.f, cnq[r >> 2][r & 3]);
                        int code = cbase + (r & 3) + 8 * (r >> 2) + 4 * h;
                        if (sc0 <= vthr[0]) {
                            int o = atomicAdd(&s_cnt[l31], 1);
                            if (o < CAP) s_cand[l31 * CAP + o] = (unsigned short)code;
                            else s_ovf[l31] = 1;
                        }
                        if (sc1 <= vthr[1]) {
                            int o = atomicAdd(&s_cnt[32 + l31], 1);
                            if (o < CAP) s_cand[(32 + l31) * CAP + o] = (unsigned short)code;
                            else s_ovf[32 + l31] = 1;
                        }
                    }
                }
            }
            if (pass == 0) {
                atomicMin(&s_vmin[l31], fmap(runmin[0]));
                atomicMin(&s_vmin[32 + l31], fmap(runmin[1]));
                __syncthreads();
                vthr[0] = funmap(s_vmin[l31]) + MARGIN;
                vthr[1] = funmap(s_vmin[32 + l31]) + MARGIN;
            }
        }
        __syncthreads();

        // ---- exact fp32 re-rank, candidate-parallel across the 4 waves ----
        // u64 atomicMin on pack = fmap(dist)<<32 | code == lexicographic
        // (dist, idx) min == numpy first-occurrence argmin; order-independent.
        {
            int vec = l;
            int n = s_cnt[vec];
            if (!s_ovf[vec]) {
                if (n == 1) {
                    if (w == 0) s_idx[vec] = s_cand[vec * CAP];
                } else {
                    const float* rv = &s_res[vec * RS];
                    float rn = s_rn[vec];
                    for (int k = w; k < n; k += 4) {
                        int c = s_cand[vec * CAP + k];
                        float dist = exact_dist(rv, cb + ((size_t)s * NC + c) * DIM,
                                                rn, s_cnorm[c]);
                        unsigned long long pack =
                            ((unsigned long long)fmap(dist) << 32) | (unsigned)c;
                        atomicMin(&s_best[vec], pack);
                    }
                }
            }
        }
        __syncthreads();
        if (tid < BM && !s_ovf[tid] && s_cnt[tid] > 1)
            s_idx[tid] = (int)(unsigned)(s_best[tid] & 0xFFFFFFFFull);
        if (tid < BM && s_ovf[tid]) {
            int p = atomicAdd(&s_ovn, 1);
            s_ovlist[p] = tid;
        }
        __syncthreads();
        // rare overflow: wave-parallel exact scan over all 1024 codes
        for (int o = w; o < s_ovn; o += 4) {
            int vec = s_ovlist[o];
            const float* rv = &s_res[vec * RS];
            float rn = s_rn[vec];
            float best = INFINITY; int bidx = 0;
            for (int k = 0; k < 16; ++k) {
                int c = k * 64 + l;  // ascending within lane
                float dist = exact_dist(rv, cb + ((size_t)s * NC + c) * DIM,
                                        rn, s_cnorm[c]);
                if (dist < best) { best = dist; bidx = c; }
            }
#pragma unroll
            for (int off = 32; off >= 1; off >>= 1) {  // lexicographic (dist, idx) min
                float ob = __shfl_xor(best, off, 64);
                int oi = __shfl_xor(bidx, off, 64);
                if (ob < best || (ob == best && oi < bidx)) { best = ob; bidx = oi; }
            }
            if (l == 0) s_idx[vec] = bidx;
        }
        __syncthreads();

        // ---- residual update in LDS (exact fp32) / final q write ----
        if (s < NS - 1) {
            for (int i4 = tid; i4 < BM * DIM / 4; i4 += 256) {
                int vec = i4 >> 5, d4 = (i4 & 31) * 4;
                int c = s_idx[vec];
                float4 cc = *(const float4*)(cb + ((size_t)s * NC + c) * DIM + d4);
                float* rp = &s_res[vec * RS + d4];
                rp[0] = rp[0] - cc.x; rp[1] = rp[1] - cc.y;
                rp[2] = rp[2] - cc.z; rp[3] = rp[3] - cc.w;
            }
        } else {  // q = x - (r - chosen), exact round-3 expression
            for (int i4 = tid; i4 < BM * DIM / 4; i4 += 256) {
                int vec = i4 >> 5, d4 = (i4 & 31) * 4;
                int c = s_idx[vec];
                float4 cc = *(const float4*)(cb + ((size_t)s * NC + c) * DIM + d4);
                float4 xx = *(const float4*)(x + (size_t)(blockbase + vec) * DIM + d4);
                const float* rp = &s_res[vec * RS + d4];
                float4 oo;
                oo.x = xx.x - (rp[0] - cc.x); oo.y = xx.y - (rp[1] - cc.y);
                oo.z = xx.z - (rp[2] - cc.z); oo.w = xx.w - (rp[3] - cc.w);
                *(float4*)(out + (size_t)(blockbase + vec) * DIM + d4) = oo;
            }
        }
        if (tid < BM)
            out[QSIZE + (size_t)s * NVEC + blockbase + tid] = (float)s_idx[tid];
        __syncthreads();
    }
}

extern "C" void kernel_launch(void* const* d_in, const int* in_sizes, int n_in,
                              void* d_out, int out_size, void* d_ws, size_t ws_size,
                              hipStream_t stream) {
    const float* x  = (const float*)d_in[0];   // [16, 8192, 128] fp32
    const float* cb = (const float*)d_in[1];   // [4, 1024, 128] fp32
    short* swz = (short*)d_ws;                                     // 1 MB
    float* cnorm = (float*)((char*)d_ws + (size_t)NS * NC * DIM * sizeof(short));
    float* out = (float*)d_out;

    rvq_norms<<<(NS * NC + 255) / 256, 256, 0, stream>>>(cb, cnorm);
    rvq_swizzle<<<NS * 32, 256, 0, stream>>>(cb, swz);
    rvq_main<<<NVEC / BM, 256, 0, stream>>>(x, cb, swz, cnorm, out);
}